// Round 1
// baseline (595.623 us; speedup 1.0000x reference)
//
#include <hip/hip_runtime.h>
#include <stdint.h>

#define MDIM 16384
#define NDIM 8192
#define KDIM 2048
#define EPS32 1.1920928955078125e-07f

using i32x4 = __attribute__((ext_vector_type(4))) int;

__device__ __forceinline__ void gload_lds16(const void* g, void* l) {
  __builtin_amdgcn_global_load_lds(
      (const __attribute__((address_space(1))) void*)g,
      (__attribute__((address_space(3))) void*)l,
      16, 0, 0);
}

__device__ __forceinline__ uint32_t sgnb(float v) { return (v < 0.f) ? 0xFFu : 0x01u; }

// ---------------------------------------------------------------------------
// Pack A signs (row-major M x K) + per-row bound a_bound[m] = max|x| + eps
// one block per row, 256 threads, 8 floats/thread
// ---------------------------------------------------------------------------
__global__ __launch_bounds__(256) void k_pack_a(const float* __restrict__ x,
                                                int8_t* __restrict__ As,
                                                float* __restrict__ ab) {
  const int m = blockIdx.x;
  const int t = threadIdx.x;
  const float4* row = (const float4*)(x + (size_t)m * KDIM);
  const float4 v0 = row[2 * t];
  const float4 v1 = row[2 * t + 1];
  const uint32_t p0 = sgnb(v0.x) | (sgnb(v0.y) << 8) | (sgnb(v0.z) << 16) | (sgnb(v0.w) << 24);
  const uint32_t p1 = sgnb(v1.x) | (sgnb(v1.y) << 8) | (sgnb(v1.z) << 16) | (sgnb(v1.w) << 24);
  ((uint2*)(As + (size_t)m * KDIM))[t] = make_uint2(p0, p1);

  float mx = fmaxf(fmaxf(fabsf(v0.x), fabsf(v0.y)), fmaxf(fabsf(v0.z), fabsf(v0.w)));
  mx = fmaxf(mx, fmaxf(fmaxf(fabsf(v1.x), fabsf(v1.y)), fmaxf(fabsf(v1.z), fabsf(v1.w))));
#pragma unroll
  for (int o = 32; o > 0; o >>= 1) mx = fmaxf(mx, __shfl_xor(mx, o, 64));
  __shared__ float red[4];
  if ((t & 63) == 0) red[t >> 6] = mx;
  __syncthreads();
  if (t == 0) ab[m] = fmaxf(fmaxf(red[0], red[1]), fmaxf(red[2], red[3])) + EPS32;
}

// ---------------------------------------------------------------------------
// w_bound[f] = max_d |W[d][f]| + eps.  Block covers 64 f, 4 d-stripes of 512.
// ---------------------------------------------------------------------------
__global__ __launch_bounds__(256) void k_wbound(const float* __restrict__ W,
                                                float* __restrict__ wb) {
  const int t = threadIdx.x;
  const int f0 = blockIdx.x * 64;
  const int fl = t & 63;
  const int stripe = t >> 6;
  const float* p = W + (size_t)(stripe * 512) * NDIM + f0 + fl;
  float m0 = 0.f, m1 = 0.f, m2 = 0.f, m3 = 0.f;
  for (int d = 0; d < 512; d += 4) {
    m0 = fmaxf(m0, fabsf(p[(size_t)d * NDIM]));
    m1 = fmaxf(m1, fabsf(p[(size_t)(d + 1) * NDIM]));
    m2 = fmaxf(m2, fabsf(p[(size_t)(d + 2) * NDIM]));
    m3 = fmaxf(m3, fabsf(p[(size_t)(d + 3) * NDIM]));
  }
  __shared__ float red[4][64];
  red[stripe][fl] = fmaxf(fmaxf(m0, m1), fmaxf(m2, m3));
  __syncthreads();
  if (t < 64) {
    const float r = fmaxf(fmaxf(red[0][t], red[1][t]), fmaxf(red[2][t], red[3][t]));
    wb[f0 + t] = r + EPS32;
  }
}

// ---------------------------------------------------------------------------
// Pack B signs transposed:  Bs[n][k] = sign(W[k][n]),  N x K row-major.
// Block handles a 64(d) x 64(f) tile via LDS transpose (rows padded to 68 B).
// ---------------------------------------------------------------------------
__global__ __launch_bounds__(256) void k_pack_b(const float* __restrict__ W,
                                                int8_t* __restrict__ Bs) {
  __shared__ char sm[64 * 68];
  const int t = threadIdx.x;
  const int bd = blockIdx.x & 31;  // 2048/64 d-tiles
  const int bf = blockIdx.x >> 5;  // 8192/64 f-tiles
  const int d0 = bd * 64, f0 = bf * 64;
  const int fl = t & 63, dq = t >> 6;
#pragma unroll
  for (int i = 0; i < 16; ++i) {
    const int dl = i * 4 + dq;
    const float v = W[(size_t)(d0 + dl) * NDIM + f0 + fl];
    sm[fl * 68 + dl] = (v < 0.f) ? (char)-1 : (char)1;
  }
  __syncthreads();
  const int nl = t >> 2, ch = t & 3;
  const uint32_t* p = (const uint32_t*)&sm[nl * 68 + ch * 16];
  uint4 o = make_uint4(p[0], p[1], p[2], p[3]);
  *(uint4*)(Bs + (size_t)(f0 + nl) * KDIM + d0 + ch * 16) = o;
}

// ---------------------------------------------------------------------------
// i8 sign-GEMM: C[m][n] = 0.25 * ab[m] * wb[n] * S + bias[n]
// 128x128 tile, 4 waves (2x2), BK=128 (two 16x16x64 k-steps per staged tile),
// global_load_lds staging with XOR-swizzled (col16 ^= row&7) LDS layout.
// ---------------------------------------------------------------------------
__global__ __launch_bounds__(256) void k_gemm(const int8_t* __restrict__ As,
                                              const int8_t* __restrict__ Bs,
                                              const float* __restrict__ ab,
                                              const float* __restrict__ wb,
                                              const float* __restrict__ bias,
                                              float* __restrict__ out) {
  __shared__ int8_t smA[128 * 128];
  __shared__ int8_t smB[128 * 128];
  const int t = threadIdx.x;
  const int lane = t & 63, wid = t >> 6;
  // bijective XCD swizzle (nwg = 8192, divisible by 8)
  const int bid = blockIdx.x;
  const int swz = (bid & 7) * (8192 / 8) + (bid >> 3);
  const int bm = swz >> 6;  // 0..127
  const int bn = swz & 63;  // 0..63
  const size_t m0 = (size_t)bm * 128, n0 = (size_t)bn * 128;
  const int wr = wid >> 1, wc = wid & 1;

  const int lrow = lane >> 3;  // row within 8-row chunk
  const int lc = lane & 7;     // col16 slot

  i32x4 acc[4][4];
#pragma unroll
  for (int i = 0; i < 4; ++i)
#pragma unroll
    for (int j = 0; j < 4; ++j) acc[i][j] = (i32x4){0, 0, 0, 0};

  const int c0 = wid * 4;
  for (int kt = 0; kt < KDIM / 128; ++kt) {
    const size_t kbase = (size_t)kt * 128;
#pragma unroll
    for (int it = 0; it < 4; ++it) {
      const int c = c0 + it;
      const int row = c * 8 + lrow;
      const int col16 = lc ^ (row & 7);  // pre-swizzled source, linear LDS dest
      gload_lds16(As + (m0 + row) * KDIM + kbase + col16 * 16, &smA[c * 1024]);
      gload_lds16(Bs + (n0 + row) * KDIM + kbase + col16 * 16, &smB[c * 1024]);
    }
    __syncthreads();
#pragma unroll
    for (int s = 0; s < 2; ++s) {
      i32x4 a[4], b[4];
#pragma unroll
      for (int i = 0; i < 4; ++i) {
        const int row = wr * 64 + i * 16 + (lane & 15);
        const int phys = (s * 4 + (lane >> 4)) ^ (row & 7);
        a[i] = *(const i32x4*)&smA[row * 128 + phys * 16];
      }
#pragma unroll
      for (int j = 0; j < 4; ++j) {
        const int nr = wc * 64 + j * 16 + (lane & 15);
        const int phys = (s * 4 + (lane >> 4)) ^ (nr & 7);
        b[j] = *(const i32x4*)&smB[nr * 128 + phys * 16];
      }
#pragma unroll
      for (int i = 0; i < 4; ++i)
#pragma unroll
        for (int j = 0; j < 4; ++j)
          acc[i][j] = __builtin_amdgcn_mfma_i32_16x16x64_i8(a[i], b[j], acc[i][j], 0, 0, 0);
    }
    __syncthreads();
  }

  // epilogue: out = 0.25*ab[m]*wb[n]*S + bias[n]
  const int colD = lane & 15, rg = lane >> 4;
#pragma unroll
  for (int i = 0; i < 4; ++i) {
    float abv[4];
#pragma unroll
    for (int r = 0; r < 4; ++r)
      abv[r] = 0.25f * ab[m0 + wr * 64 + i * 16 + rg * 4 + r];
#pragma unroll
    for (int j = 0; j < 4; ++j) {
      const size_t n = n0 + wc * 64 + j * 16 + colD;
      const float wv = wb[n];
      const float bv = bias[n];
#pragma unroll
      for (int r = 0; r < 4; ++r) {
        const size_t m = m0 + wr * 64 + i * 16 + rg * 4 + r;
        out[m * NDIM + n] = abv[r] * (wv * (float)acc[i][j][r]) + bv;
      }
    }
  }
}

extern "C" void kernel_launch(void* const* d_in, const int* in_sizes, int n_in,
                              void* d_out, int out_size, void* d_ws, size_t ws_size,
                              hipStream_t stream) {
  const float* x = (const float*)d_in[0];     // (4, 4096, 2048)
  const float* W = (const float*)d_in[1];     // (2048, 8192)
  const float* bias = (const float*)d_in[2];  // (8192,)
  float* out = (float*)d_out;

  char* ws = (char*)d_ws;
  int8_t* As = (int8_t*)ws;                               // 32 MiB
  int8_t* Bs = (int8_t*)(ws + (size_t)(32u << 20));       // 16 MiB
  float* ab = (float*)(ws + (size_t)(48u << 20));         // 64 KiB
  float* wb = (float*)(ws + (size_t)(48u << 20) + (1u << 16));  // 32 KiB

  k_pack_a<<<MDIM, 256, 0, stream>>>(x, As, ab);
  k_wbound<<<NDIM / 64, 256, 0, stream>>>(W, wb);
  k_pack_b<<<(KDIM / 64) * (NDIM / 64), 256, 0, stream>>>(W, Bs);
  k_gemm<<<(MDIM / 128) * (NDIM / 128), 256, 0, stream>>>(As, Bs, ab, wb, bias, out);
}

// Round 2
// 436.863 us; speedup vs baseline: 1.3634x; 1.3634x over previous
//
#include <hip/hip_runtime.h>
#include <stdint.h>

#define MDIM 16384
#define NDIM 8192
#define KDIM 2048
#define EPS32 1.1920928955078125e-07f
#define BM 256
#define BN 256
#define BK 64

using i32x4 = __attribute__((ext_vector_type(4))) int;

__device__ __forceinline__ void gload_lds16(const void* g, void* l) {
  __builtin_amdgcn_global_load_lds(
      (const __attribute__((address_space(1))) void*)g,
      (__attribute__((address_space(3))) void*)l,
      16, 0, 0);
}

__device__ __forceinline__ uint32_t sgnb(float v) { return (v < 0.f) ? 0xFFu : 0x01u; }

// ---------------------------------------------------------------------------
// Pack A signs (M x K) + per-row bound ab[m] = max|x| + eps
// ---------------------------------------------------------------------------
__global__ __launch_bounds__(256) void k_pack_a(const float* __restrict__ x,
                                                int8_t* __restrict__ As,
                                                float* __restrict__ ab) {
  const int m = blockIdx.x;
  const int t = threadIdx.x;
  const float4* row = (const float4*)(x + (size_t)m * KDIM);
  const float4 v0 = row[2 * t];
  const float4 v1 = row[2 * t + 1];
  const uint32_t p0 = sgnb(v0.x) | (sgnb(v0.y) << 8) | (sgnb(v0.z) << 16) | (sgnb(v0.w) << 24);
  const uint32_t p1 = sgnb(v1.x) | (sgnb(v1.y) << 8) | (sgnb(v1.z) << 16) | (sgnb(v1.w) << 24);
  ((uint2*)(As + (size_t)m * KDIM))[t] = make_uint2(p0, p1);

  float mx = fmaxf(fmaxf(fabsf(v0.x), fabsf(v0.y)), fmaxf(fabsf(v0.z), fabsf(v0.w)));
  mx = fmaxf(mx, fmaxf(fmaxf(fabsf(v1.x), fabsf(v1.y)), fmaxf(fabsf(v1.z), fabsf(v1.w))));
#pragma unroll
  for (int o = 32; o > 0; o >>= 1) mx = fmaxf(mx, __shfl_xor(mx, o, 64));
  __shared__ float red[4];
  if ((t & 63) == 0) red[t >> 6] = mx;
  __syncthreads();
  if (t == 0) ab[m] = fmaxf(fmaxf(red[0], red[1]), fmaxf(red[2], red[3])) + EPS32;
}

// ---------------------------------------------------------------------------
// Pack B signs transposed (Bs[n][k] = sign(W[k][n])) FUSED with per-column
// max: atomicMax(wb[f], |W|) on float-as-uint bits (order-preserving, >=0).
// ---------------------------------------------------------------------------
__global__ __launch_bounds__(256) void k_pack_b(const float* __restrict__ W,
                                                int8_t* __restrict__ Bs,
                                                unsigned int* __restrict__ wbu) {
  __shared__ char sm[64 * 68];
  __shared__ float red[4][64];
  const int t = threadIdx.x;
  const int bd = blockIdx.x & 31;  // 2048/64 d-tiles
  const int bf = blockIdx.x >> 5;  // 8192/64 f-tiles
  const int d0 = bd * 64, f0 = bf * 64;
  const int fl = t & 63, dq = t >> 6;
  float mx = 0.f;
#pragma unroll
  for (int i = 0; i < 16; ++i) {
    const int dl = i * 4 + dq;
    const float v = W[(size_t)(d0 + dl) * NDIM + f0 + fl];
    sm[fl * 68 + dl] = (v < 0.f) ? (char)-1 : (char)1;
    mx = fmaxf(mx, fabsf(v));
  }
  red[dq][fl] = mx;
  __syncthreads();
  if (t < 64) {
    const float r = fmaxf(fmaxf(red[0][t], red[1][t]), fmaxf(red[2][t], red[3][t]));
    atomicMax(&wbu[f0 + t], __float_as_uint(r));
  }
  const int nl = t >> 2, ch = t & 3;
  const uint32_t* p = (const uint32_t*)&sm[nl * 68 + ch * 16];
  uint4 o = make_uint4(p[0], p[1], p[2], p[3]);
  *(uint4*)(Bs + (size_t)(f0 + nl) * KDIM + d0 + ch * 16) = o;
}

// ---------------------------------------------------------------------------
// i8 sign-GEMM, 256x256 tile, 8 waves (2x4), BK=64, 4-slot LDS ring,
// counted vmcnt(8) pipeline (T3+T4), setprio around MFMA (T5), XOR-swizzled
// LDS (T2, source-side for global_load_lds + identical read-side).
// C[m][n] = 0.25 * ab[m] * (wb[n]+eps) * S + bias[n]
// ---------------------------------------------------------------------------
__global__ __launch_bounds__(512, 2) void k_gemm(const int8_t* __restrict__ As,
                                                 const int8_t* __restrict__ Bs,
                                                 const float* __restrict__ ab,
                                                 const float* __restrict__ wbf,
                                                 const float* __restrict__ bias,
                                                 float* __restrict__ out) {
  __shared__ int8_t lds[4][32768];  // ring slot: A 16KB | B 16KB
  const int t = threadIdx.x;
  const int lane = t & 63, wid = t >> 6;
  const int bid = blockIdx.x;
  const int swz = (bid & 7) * 256 + (bid >> 3);  // nwg=2048, %8==0: bijective
  const int bm = swz >> 5;                       // 0..63
  const int bn = swz & 31;                       // 0..31
  const size_t m0 = (size_t)bm * BM, n0 = (size_t)bn * BN;
  const int wr = wid >> 2, wc = wid & 3;

  // staging: chunk = 16 rows x 64B = 1KB per wave-instruction; wave wid owns
  // chunks {2*wid, 2*wid+1} of each operand. Source pre-swizzled: logical
  // 16B-slot = (lane&3) ^ ((row_in_chunk>>1)&3); LDS dest linear.
  const int srow = lane >> 2;
  const int sl = (lane & 3) ^ ((lane >> 3) & 3);
  const int8_t* gA0 = As + (m0 + (size_t)(wid * 32 + srow)) * KDIM + sl * 16;
  const int8_t* gA1 = gA0 + (size_t)16 * KDIM;
  const int8_t* gB0 = Bs + (n0 + (size_t)(wid * 32 + srow)) * KDIM + sl * 16;
  const int8_t* gB1 = gB0 + (size_t)16 * KDIM;

  // ds_read fragment addressing (swizzle identical to staging permutation)
  const int l15 = lane & 15;
  const int p = (lane >> 4) ^ ((l15 >> 1) & 3);
  const int aoff = (wr * 128 + l15) * 64 + p * 16;         // + i*1024
  const int boff = 16384 + (wc * 64 + l15) * 64 + p * 16;  // + j*1024

  i32x4 acc[8][4];
#pragma unroll
  for (int i = 0; i < 8; ++i)
#pragma unroll
    for (int j = 0; j < 4; ++j) acc[i][j] = (i32x4){0, 0, 0, 0};

#define ISSUE_A(u)                                                      \
  do {                                                                  \
    int8_t* dA = &lds[(u) & 3][wid * 2048];                             \
    gload_lds16(gA0 + (size_t)(u) * BK, dA);                            \
    gload_lds16(gA1 + (size_t)(u) * BK, dA + 1024);                     \
  } while (0)
#define ISSUE_B(u)                                                      \
  do {                                                                  \
    int8_t* dB = &lds[(u) & 3][16384 + wid * 2048];                     \
    gload_lds16(gB0 + (size_t)(u) * BK, dB);                            \
    gload_lds16(gB1 + (size_t)(u) * BK, dB + 1024);                     \
  } while (0)

#define ITER(TT, DOISSUE, WAIT_TAIL)                                         \
  {                                                                          \
    const int8_t* sA = lds[(TT) & 3];                                        \
    i32x4 af[4], bf[4];                                                      \
    /* phase 0: prefetch A(TT+3) || ds_read A0-3,B0-3 || MFMA quad 0 */      \
    if (DOISSUE) ISSUE_A((TT) + 3);                                          \
    _Pragma("unroll") for (int i = 0; i < 4; ++i)                            \
        af[i] = *(const i32x4*)(sA + aoff + i * 1024);                       \
    _Pragma("unroll") for (int j = 0; j < 4; ++j)                            \
        bf[j] = *(const i32x4*)(sA + boff + j * 1024);                       \
    __builtin_amdgcn_s_barrier();                                            \
    asm volatile("s_waitcnt lgkmcnt(0)" ::: "memory");                       \
    __builtin_amdgcn_sched_barrier(0);                                       \
    __builtin_amdgcn_s_setprio(1);                                           \
    _Pragma("unroll") for (int i = 0; i < 4; ++i)                            \
        _Pragma("unroll") for (int j = 0; j < 4; ++j) acc[i][j] =            \
            __builtin_amdgcn_mfma_i32_16x16x64_i8(af[i], bf[j], acc[i][j],   \
                                                  0, 0, 0);                  \
    __builtin_amdgcn_s_setprio(0);                                           \
    __builtin_amdgcn_s_barrier();                                            \
    /* phase 1: prefetch B(TT+3) || ds_read A4-7 || MFMA quad 1 */           \
    if (DOISSUE) ISSUE_B((TT) + 3);                                          \
    _Pragma("unroll") for (int i = 0; i < 4; ++i)                            \
        af[i] = *(const i32x4*)(sA + aoff + 4096 + i * 1024);                \
    __builtin_amdgcn_s_barrier();                                            \
    asm volatile("s_waitcnt lgkmcnt(0)" ::: "memory");                       \
    __builtin_amdgcn_sched_barrier(0);                                       \
    __builtin_amdgcn_s_setprio(1);                                           \
    _Pragma("unroll") for (int i = 0; i < 4; ++i)                            \
        _Pragma("unroll") for (int j = 0; j < 4; ++j) acc[4 + i][j] =        \
            __builtin_amdgcn_mfma_i32_16x16x64_i8(af[i], bf[j],              \
                                                  acc[4 + i][j], 0, 0, 0);   \
    __builtin_amdgcn_s_setprio(0);                                           \
    asm volatile(WAIT_TAIL ::: "memory");                                    \
    __builtin_amdgcn_s_barrier();                                            \
  }

  // prologue: stage tiles 0,1,2 into ring slots 0,1,2 (12 loads/wave)
  ISSUE_A(0); ISSUE_B(0);
  ISSUE_A(1); ISSUE_B(1);
  ISSUE_A(2); ISSUE_B(2);
  asm volatile("s_waitcnt vmcnt(8)" ::: "memory");  // tile 0 landed
  __builtin_amdgcn_s_barrier();

#pragma unroll 4
  for (int tt = 0; tt < 28; ++tt) ITER(tt, true, "s_waitcnt vmcnt(8)");
  ITER(28, true, "s_waitcnt vmcnt(8)");   // issues tile 31
  ITER(29, false, "s_waitcnt vmcnt(4)");
  ITER(30, false, "s_waitcnt vmcnt(0)");
  ITER(31, false, "");

  // epilogue: out = 0.25*ab[m]*(wb[n]+eps)*S + bias[n]
  const int colD = lane & 15, rg = lane >> 4;
#pragma unroll
  for (int i = 0; i < 8; ++i) {
    const size_t mrow = m0 + wr * 128 + i * 16 + rg * 4;
    float abv[4];
#pragma unroll
    for (int r = 0; r < 4; ++r) abv[r] = 0.25f * ab[mrow + r];
#pragma unroll
    for (int j = 0; j < 4; ++j) {
      const size_t n = n0 + wc * 64 + j * 16 + colD;
      const float wv = wbf[n] + EPS32;
      const float bv = bias[n];
#pragma unroll
      for (int r = 0; r < 4; ++r)
        out[(mrow + r) * NDIM + n] = abv[r] * (wv * (float)acc[i][j][r]) + bv;
    }
  }
#undef ITER
#undef ISSUE_A
#undef ISSUE_B
}

extern "C" void kernel_launch(void* const* d_in, const int* in_sizes, int n_in,
                              void* d_out, int out_size, void* d_ws, size_t ws_size,
                              hipStream_t stream) {
  const float* x = (const float*)d_in[0];     // (4, 4096, 2048)
  const float* W = (const float*)d_in[1];     // (2048, 8192)
  const float* bias = (const float*)d_in[2];  // (8192,)
  float* out = (float*)d_out;

  char* ws = (char*)d_ws;
  int8_t* As = (int8_t*)ws;                                     // 32 MiB
  int8_t* Bs = (int8_t*)(ws + (size_t)(32u << 20));             // 16 MiB
  float* ab = (float*)(ws + (size_t)(48u << 20));               // 64 KiB
  float* wb = (float*)(ws + (size_t)(48u << 20) + (1u << 16));  // 32 KiB

  hipMemsetAsync(wb, 0, NDIM * sizeof(float), stream);
  k_pack_a<<<MDIM, 256, 0, stream>>>(x, As, ab);
  k_pack_b<<<(KDIM / 64) * (NDIM / 64), 256, 0, stream>>>(W, Bs, (unsigned int*)wb);
  k_gemm<<<(MDIM / BM) * (NDIM / BN), 512, 0, stream>>>(As, Bs, ab, wb, bias, out);
}

// Round 4
// 376.171 us; speedup vs baseline: 1.5834x; 1.1613x over previous
//
#include <hip/hip_runtime.h>
#include <stdint.h>

#define MDIM 16384
#define NDIM 8192
#define KDIM 2048
#define EPS32 1.1920928955078125e-07f
#define BM 256
#define BN 256
#define BK 64

using i32x4 = __attribute__((ext_vector_type(4))) int;
using f32x4 = __attribute__((ext_vector_type(4))) float;
typedef __attribute__((address_space(3))) const int8_t* lds_cptr;

__device__ __forceinline__ void gload_lds16(const void* g, void* l) {
  __builtin_amdgcn_global_load_lds(
      (const __attribute__((address_space(1))) void*)g,
      (__attribute__((address_space(3))) void*)l,
      16, 0, 0);
}

__device__ __forceinline__ uint32_t sgnb(float v) { return (v < 0.f) ? 0xFFu : 0x01u; }

// ---------------------------------------------------------------------------
// Fused pack: blocks [0,MDIM) pack A rows + ab[m]; blocks [MDIM, MDIM+2048)
// pack B transposed tiles + atomicMax column bound.
// ---------------------------------------------------------------------------
__global__ __launch_bounds__(256) void k_pack(const float* __restrict__ x,
                                              const float* __restrict__ W,
                                              int8_t* __restrict__ As,
                                              int8_t* __restrict__ Bs,
                                              float* __restrict__ ab,
                                              unsigned int* __restrict__ wbu) {
  __shared__ char sm[64 * 68];
  __shared__ float red[4][64];
  const int t = threadIdx.x;
  if (blockIdx.x < MDIM) {
    const int m = blockIdx.x;
    const float4* row = (const float4*)(x + (size_t)m * KDIM);
    const float4 v0 = row[2 * t];
    const float4 v1 = row[2 * t + 1];
    const uint32_t p0 = sgnb(v0.x) | (sgnb(v0.y) << 8) | (sgnb(v0.z) << 16) | (sgnb(v0.w) << 24);
    const uint32_t p1 = sgnb(v1.x) | (sgnb(v1.y) << 8) | (sgnb(v1.z) << 16) | (sgnb(v1.w) << 24);
    ((uint2*)(As + (size_t)m * KDIM))[t] = make_uint2(p0, p1);
    float mx = fmaxf(fmaxf(fabsf(v0.x), fabsf(v0.y)), fmaxf(fabsf(v0.z), fabsf(v0.w)));
    mx = fmaxf(mx, fmaxf(fmaxf(fabsf(v1.x), fabsf(v1.y)), fmaxf(fabsf(v1.z), fabsf(v1.w))));
#pragma unroll
    for (int o = 32; o > 0; o >>= 1) mx = fmaxf(mx, __shfl_xor(mx, o, 64));
    if ((t & 63) == 0) red[0][t >> 6] = mx;
    __syncthreads();
    if (t == 0)
      ab[m] = fmaxf(fmaxf(red[0][0], red[0][1]), fmaxf(red[0][2], red[0][3])) + EPS32;
  } else {
    const int bid = blockIdx.x - MDIM;
    const int bd = bid & 31;  // 2048/64 d-tiles
    const int bf = bid >> 5;  // 8192/64 f-tiles
    const int d0 = bd * 64, f0 = bf * 64;
    const int fl = t & 63, dq = t >> 6;
    float mx = 0.f;
#pragma unroll
    for (int i = 0; i < 16; ++i) {
      const int dl = i * 4 + dq;
      const float v = W[(size_t)(d0 + dl) * NDIM + f0 + fl];
      sm[fl * 68 + dl] = (v < 0.f) ? (char)-1 : (char)1;
      mx = fmaxf(mx, fabsf(v));
    }
    red[dq][fl] = mx;
    __syncthreads();
    if (t < 64) {
      const float r = fmaxf(fmaxf(red[0][t], red[1][t]), fmaxf(red[2][t], red[3][t]));
      atomicMax(&wbu[f0 + t], __float_as_uint(r));
    }
    const int nl = t >> 2, ch = t & 3;
    const uint32_t* p = (const uint32_t*)&sm[nl * 68 + ch * 16];
    uint4 o = make_uint4(p[0], p[1], p[2], p[3]);
    *(uint4*)(Bs + (size_t)(f0 + nl) * KDIM + d0 + ch * 16) = o;
  }
}

// ---------------------------------------------------------------------------
// i8 sign-GEMM, 256x256 tile, 8 waves (2x4), BK=64, 4-slot LDS ring,
// counted vmcnt(8) global pipeline + counted lgkmcnt MFMA/LDS interleave,
// swapped-operand MFMA (D rows = n) -> f32x4 nontemporal epilogue.
// C[m][n] = 0.25 * ab[m] * (wb[n]+eps) * S + bias[n]
// ---------------------------------------------------------------------------
__global__ __launch_bounds__(512, 2) void k_gemm(const int8_t* __restrict__ As,
                                                 const int8_t* __restrict__ Bs,
                                                 const float* __restrict__ ab,
                                                 const float* __restrict__ wbf,
                                                 const float* __restrict__ bias,
                                                 float* __restrict__ out) {
  __shared__ int8_t lds[4][32768];  // ring slot: A 16KB | B 16KB
  const int t = threadIdx.x;
  const int lane = t & 63, wid = t >> 6;
  const int bid = blockIdx.x;
  const int swz = (bid & 7) * 256 + (bid >> 3);  // nwg=2048, %8==0: bijective
  const int bm = swz >> 5;                       // 0..63
  const int bn = swz & 31;                       // 0..31
  const size_t m0 = (size_t)bm * BM, n0 = (size_t)bn * BN;
  const int wr = wid >> 2, wc = wid & 3;

  // staging: source pre-swizzled 16B-slot = (lane&3) ^ ((row>>1)&3); LDS linear
  const int srow = lane >> 2;
  const int sl = (lane & 3) ^ ((lane >> 3) & 3);
  const int8_t* gA0 = As + (m0 + (size_t)(wid * 32 + srow)) * KDIM + sl * 16;
  const int8_t* gA1 = gA0 + (size_t)16 * KDIM;
  const int8_t* gB0 = Bs + (n0 + (size_t)(wid * 32 + srow)) * KDIM + sl * 16;
  const int8_t* gB1 = gB0 + (size_t)16 * KDIM;

  // ds_read addressing: read-side XOR cancels write-side permutation
  const int l15 = lane & 15;
  const int p = (lane >> 4) ^ ((l15 >> 1) & 3);
  const int aoff = (wr * 128 + l15) * 64 + p * 16;
  const int boff = 16384 + (wc * 64 + l15) * 64 + p * 16;

  i32x4 acc[8][4];
#pragma unroll
  for (int i = 0; i < 8; ++i)
#pragma unroll
    for (int j = 0; j < 4; ++j) acc[i][j] = (i32x4){0, 0, 0, 0};

#define ISSUE_A(u)                                      \
  do {                                                  \
    int8_t* dA = &lds[(u) & 3][wid * 2048];             \
    gload_lds16(gA0 + (size_t)(u) * BK, dA);            \
    gload_lds16(gA1 + (size_t)(u) * BK, dA + 1024);     \
  } while (0)
#define ISSUE_B(u)                                      \
  do {                                                  \
    int8_t* dB = &lds[(u) & 3][16384 + wid * 2048];     \
    gload_lds16(gB0 + (size_t)(u) * BK, dB);            \
    gload_lds16(gB1 + (size_t)(u) * BK, dB + 1024);     \
  } while (0)

#define DSR(dst, ptr, OFF) \
  asm volatile("ds_read_b128 %0, %1 offset:" #OFF : "=v"(dst) : "v"(ptr))

// swapped operands: D rows = n (b-frag first), cols = m
#define MROW(R, AF)                                                               \
  acc[R][0] = __builtin_amdgcn_mfma_i32_16x16x64_i8(b0, AF, acc[R][0], 0, 0, 0);  \
  acc[R][1] = __builtin_amdgcn_mfma_i32_16x16x64_i8(b1, AF, acc[R][1], 0, 0, 0);  \
  acc[R][2] = __builtin_amdgcn_mfma_i32_16x16x64_i8(b2, AF, acc[R][2], 0, 0, 0);  \
  acc[R][3] = __builtin_amdgcn_mfma_i32_16x16x64_i8(b3, AF, acc[R][3], 0, 0, 0);

#define LGK(N)                                              \
  asm volatile("s_waitcnt lgkmcnt(" #N ")" ::: "memory");   \
  __builtin_amdgcn_sched_barrier(0);

#define ITER(TT, DOISSUE, WAIT_TAIL)                                          \
  {                                                                           \
    lds_cptr pA = (lds_cptr)(&lds[(TT) & 3][0] + aoff);                       \
    lds_cptr pB = (lds_cptr)(&lds[(TT) & 3][0] + boff);                       \
    i32x4 a0, a1, a2, a3, b0, b1, b2, b3;                                     \
    if (DOISSUE) ISSUE_A((TT) + 3);                                           \
    DSR(a0, pA, 0);                                                           \
    DSR(b0, pB, 0); DSR(b1, pB, 1024); DSR(b2, pB, 2048); DSR(b3, pB, 3072);  \
    DSR(a1, pA, 1024); DSR(a2, pA, 2048); DSR(a3, pA, 3072);                  \
    __builtin_amdgcn_s_barrier();                                             \
    LGK(3); __builtin_amdgcn_s_setprio(1); MROW(0, a0);                       \
    LGK(2); MROW(1, a1);                                                      \
    LGK(1); MROW(2, a2);                                                      \
    LGK(0); MROW(3, a3);                                                      \
    __builtin_amdgcn_s_setprio(0);                                            \
    __builtin_amdgcn_s_barrier();                                             \
    if (DOISSUE) ISSUE_B((TT) + 3);                                           \
    DSR(a0, pA, 4096); DSR(a1, pA, 5120); DSR(a2, pA, 6144); DSR(a3, pA, 7168); \
    __builtin_amdgcn_s_barrier();                                             \
    LGK(3); __builtin_amdgcn_s_setprio(1); MROW(4, a0);                       \
    LGK(2); MROW(5, a1);                                                      \
    LGK(1); MROW(6, a2);                                                      \
    LGK(0); MROW(7, a3);                                                      \
    __builtin_amdgcn_s_setprio(0);                                            \
    asm volatile(WAIT_TAIL ::: "memory");                                     \
    __builtin_amdgcn_s_barrier();                                             \
  }

  // prologue: stage tiles 0,1,2 into ring slots 0,1,2
  ISSUE_A(0); ISSUE_B(0);
  ISSUE_A(1); ISSUE_B(1);
  ISSUE_A(2); ISSUE_B(2);
  asm volatile("s_waitcnt vmcnt(8)" ::: "memory");  // tile 0 landed
  __builtin_amdgcn_s_barrier();

#pragma unroll 2
  for (int tt = 0; tt < 28; ++tt) ITER(tt, true, "s_waitcnt vmcnt(8)");
  ITER(28, true, "s_waitcnt vmcnt(8)");   // issues tile 31
  ITER(29, false, "s_waitcnt vmcnt(4)");
  ITER(30, false, "s_waitcnt vmcnt(0)");
  ITER(31, false, "s_nop 0");

  // epilogue: lane owns 4 consecutive n -> f32x4 nontemporal stores
  const int rg = lane >> 4;
#pragma unroll
  for (int i = 0; i < 8; ++i) {
    const size_t m = m0 + wr * 128 + i * 16 + l15;
    const float av = 0.25f * ab[m];
    float* orow = out + m * NDIM;
#pragma unroll
    for (int j = 0; j < 4; ++j) {
      const size_t nb = n0 + wc * 64 + j * 16 + rg * 4;
      const f32x4 wv = *(const f32x4*)&wbf[nb];
      const f32x4 bv = *(const f32x4*)&bias[nb];
      f32x4 o;
      o[0] = av * ((wv[0] + EPS32) * (float)acc[i][j][0]) + bv[0];
      o[1] = av * ((wv[1] + EPS32) * (float)acc[i][j][1]) + bv[1];
      o[2] = av * ((wv[2] + EPS32) * (float)acc[i][j][2]) + bv[2];
      o[3] = av * ((wv[3] + EPS32) * (float)acc[i][j][3]) + bv[3];
      __builtin_nontemporal_store(o, (f32x4*)(orow + nb));
    }
  }
#undef ITER
#undef LGK
#undef MROW
#undef DSR
#undef ISSUE_A
#undef ISSUE_B
}

extern "C" void kernel_launch(void* const* d_in, const int* in_sizes, int n_in,
                              void* d_out, int out_size, void* d_ws, size_t ws_size,
                              hipStream_t stream) {
  const float* x = (const float*)d_in[0];     // (4, 4096, 2048)
  const float* W = (const float*)d_in[1];     // (2048, 8192)
  const float* bias = (const float*)d_in[2];  // (8192,)
  float* out = (float*)d_out;

  char* ws = (char*)d_ws;
  int8_t* As = (int8_t*)ws;                                     // 32 MiB
  int8_t* Bs = (int8_t*)(ws + (size_t)(32u << 20));             // 16 MiB
  float* ab = (float*)(ws + (size_t)(48u << 20));               // 64 KiB
  float* wb = (float*)(ws + (size_t)(48u << 20) + (1u << 16));  // 32 KiB

  (void)hipMemsetAsync(wb, 0, NDIM * sizeof(float), stream);
  k_pack<<<MDIM + (KDIM / 64) * (NDIM / 64), 256, 0, stream>>>(x, W, As, Bs, ab,
                                                               (unsigned int*)wb);
  k_gemm<<<(MDIM / BM) * (NDIM / BN), 512, 0, stream>>>(As, Bs, ab, wb, bias, out);
}